// Round 2
// 5024.615 us; speedup vs baseline: 1.1317x; 1.1317x over previous
//
#include <hip/hip_runtime.h>

#define B_  32
#define L_  2048
#define IN_ 512
#define H_  512
#define C_  1000

typedef __bf16 bf16x8 __attribute__((ext_vector_type(8)));
typedef short  short8 __attribute__((ext_vector_type(8)));
typedef float  floatx4 __attribute__((ext_vector_type(4)));

__device__ __forceinline__ unsigned short f2bf(float x) {
    unsigned u = __builtin_bit_cast(unsigned, x);
    unsigned r = (u + 0x7fffu + ((u >> 16) & 1u)) >> 16;
    return (unsigned short)r;
}
__device__ __forceinline__ float bf2f(unsigned short s) {
    unsigned u = ((unsigned)s) << 16;
    return __builtin_bit_cast(float, u);
}

// ---------------------------------------------------------------------------
// Generic C[M x Nreal] = A[M x 512] * W[Nreal x 512]^T + bias, fp32 in/out,
// bf16 MFMA compute. grid = (Ntiles, Mtiles), block = 256 (4 waves, 2x2).
// ---------------------------------------------------------------------------
__global__ __launch_bounds__(256) void gemm_bias(
    const float* __restrict__ A, const float* __restrict__ W,
    const float* __restrict__ bias, float* __restrict__ Cc,
    int ldc, int Nreal)
{
    __shared__ unsigned short As[128 * 40];   // [row][k], k-pad 32->40
    __shared__ unsigned short Bs[128 * 40];   // [nrow][k]

    const int tid  = threadIdx.x;
    const int lane = tid & 63;
    const int wv   = tid >> 6;       // 0..3
    const int wm   = wv >> 1;        // row half
    const int wn   = wv & 1;         // col half
    const int quad = lane >> 4;
    const long mbase = (long)blockIdx.y * 128;
    const int  nbase = blockIdx.x * 128;

    floatx4 acc[4][4];
#pragma unroll
    for (int mt = 0; mt < 4; ++mt)
#pragma unroll
        for (int nt = 0; nt < 4; ++nt)
            acc[mt][nt] = (floatx4){0.f, 0.f, 0.f, 0.f};

    for (int kt = 0; kt < 16; ++kt) {
        const int kbase = kt * 32;
#pragma unroll
        for (int i = 0; i < 4; ++i) {
            const int f  = tid + i * 256;       // 0..1023 float4 slots
            const int r  = f >> 3;              // 0..127
            const int c4 = f & 7;               // 0..7
            const float4 va = *(const float4*)(A + (mbase + r) * 512 + kbase + c4 * 4);
            unsigned alo = (unsigned)f2bf(va.x) | ((unsigned)f2bf(va.y) << 16);
            unsigned ahi = (unsigned)f2bf(va.z) | ((unsigned)f2bf(va.w) << 16);
            *(uint2*)(&As[r * 40 + c4 * 4]) = make_uint2(alo, ahi);

            const int n_g = nbase + r;
            float4 vb;
            if (n_g < Nreal) vb = *(const float4*)(W + (long)n_g * 512 + kbase + c4 * 4);
            else             vb = make_float4(0.f, 0.f, 0.f, 0.f);
            unsigned blo = (unsigned)f2bf(vb.x) | ((unsigned)f2bf(vb.y) << 16);
            unsigned bhi = (unsigned)f2bf(vb.z) | ((unsigned)f2bf(vb.w) << 16);
            *(uint2*)(&Bs[r * 40 + c4 * 4]) = make_uint2(blo, bhi);
        }
        __syncthreads();

        bf16x8 af[4], bfr[4];
#pragma unroll
        for (int mt = 0; mt < 4; ++mt)
            af[mt] = *(const bf16x8*)(&As[(wm * 64 + mt * 16 + (lane & 15)) * 40 + quad * 8]);
#pragma unroll
        for (int nt = 0; nt < 4; ++nt)
            bfr[nt] = *(const bf16x8*)(&Bs[(wn * 64 + nt * 16 + (lane & 15)) * 40 + quad * 8]);
#pragma unroll
        for (int mt = 0; mt < 4; ++mt)
#pragma unroll
            for (int nt = 0; nt < 4; ++nt)
                acc[mt][nt] = __builtin_amdgcn_mfma_f32_16x16x32_bf16(
                    af[mt], bfr[nt], acc[mt][nt], 0, 0, 0);
        __syncthreads();
    }

#pragma unroll
    for (int nt = 0; nt < 4; ++nt) {
        const int col = nbase + wn * 64 + nt * 16 + (lane & 15);
        if (col < Nreal) {
            const float bv = bias[col];
#pragma unroll
            for (int mt = 0; mt < 4; ++mt) {
#pragma unroll
                for (int i = 0; i < 4; ++i) {
                    const long row = mbase + wm * 64 + mt * 16 + quad * 4 + i;
                    Cc[row * (long)ldc + col] = acc[mt][nt][i] + bv;
                }
            }
        }
    }
}

// ---------------------------------------------------------------------------
// Recurrence: 64 WGs x 256 threads. group = wg>>3 (4 batches), slice = wg&7
// (64 output rows). Wh slice lives in VGPRs as B-fragments. h exchanged per
// step via TAGGED lock-free u64 slots in an IF-resident double buffer.
//
//  * u64 payload is PRODUCER-PACKED bf16: (tag32 << 32) | (hi16 << 16) | lo16.
//    Consumer staging = 2 bit-extracts + 2 ds_write_b16, no float math.
//  * hi/lo error-correction packed as A-ROWS 0-3 (hi) / 4-7 (lo) of ONE
//    16-row MFMA tile -> 16 MFMAs + 16 ds_read_b128 per step (was 32+32).
//    D rows r and r+4 are summed in the epilogue via shfl_xor(.,16) --
//    numerically identical (both chains f32-accumulated independently).
//  * all 16 A-fragments prefetched to VGPRs before the MFMA chain (2
//    interleaved even/odd-kk accumulator chains) -> no exposed LDS latency
//    at 1 wave/SIMD.
//  * LDS staging double-buffered -> ONE __syncthreads per step. Safety: a
//    wave re-stages buffer p at step t+2 only after barrier(t+1), which
//    proves every wave finished its step-t reads of buffer p. Cross-WG
//    2-buffer parity argument unchanged: publish(t+1) transitively requires
//    all peers consumed t-1.
// ---------------------------------------------------------------------------
__global__ __launch_bounds__(256, 1) void rnn_scan(
    const float* __restrict__ Wh, const float* __restrict__ bh,
    const float* __restrict__ hidden, const float* __restrict__ xp,
    float* __restrict__ hn, unsigned long long* exch)
{
    // rows 0-3 = h_hi (batch 0-3), rows 4-7 = h_lo (batch 0-3), row 8 = zeros
    __shared__ unsigned short lds_h[2][9 * 520];

    const int tid   = threadIdx.x;
    const int lane  = tid & 63;
    const int wv    = tid >> 6;        // wave = ntile 0..3
    const int wg    = blockIdx.x;      // 0..63
    const int group = wg >> 3;         // 0..7
    const int slice = wg & 7;          // 0..7
    const int b0    = group * 4;
    const int n0    = slice * 64;
    const int quad  = lane >> 4;
    const int rr    = ((lane & 15) < 8) ? (lane & 15) : 8;   // A row (zero-pad)

    // exch layout: [group 8][parity 2][elem 2048] u64; elem = batch*512 + col

    // ---- load Wh B-fragments once (bf16, in VGPRs) ----
    bf16x8 wf[16];
    {
        const int n_row = n0 + wv * 16 + (lane & 15);
#pragma unroll
        for (int kk = 0; kk < 16; ++kk) {
            const float4 w0 = *(const float4*)(Wh + (long)n_row * 512 + kk * 32 + quad * 8);
            const float4 w1 = *(const float4*)(Wh + (long)n_row * 512 + kk * 32 + quad * 8 + 4);
            short8 s;
            s[0] = (short)f2bf(w0.x); s[1] = (short)f2bf(w0.y);
            s[2] = (short)f2bf(w0.z); s[3] = (short)f2bf(w0.w);
            s[4] = (short)f2bf(w1.x); s[5] = (short)f2bf(w1.y);
            s[6] = (short)f2bf(w1.z); s[7] = (short)f2bf(w1.w);
            wf[kk] = __builtin_bit_cast(bf16x8, s);
        }
    }

    const int   n_lane = n0 + wv * 16 + (lane & 15);   // output col this lane handles
    const int   b_lane = b0 + quad;                    // batch this lane handles
    const float bias_v = bh[n_lane];

    // ---- initial stage: zero pad row (both buffers), h0 from hidden[:,0,:] ----
    for (int i = tid; i < 520; i += 256) {
        lds_h[0][8 * 520 + i] = 0;
        lds_h[1][8 * 520 + i] = 0;
    }
#pragma unroll
    for (int i = 0; i < 8; ++i) {
        const int idx = tid + i * 256;          // 0..2047
        const int r = idx >> 9, c = idx & 511;
        const float v = hidden[((long)(b0 + r) * L_) * H_ + c];
        const unsigned short hv = f2bf(v);
        lds_h[0][r * 520 + c]       = hv;
        lds_h[0][(r + 4) * 520 + c] = f2bf(v - bf2f(hv));
    }

    for (int t = 0; t < L_; ++t) {
        // xp for this step (issued early; arrives during poll/MFMA)
        const float xpv = xp[((long)b_lane * L_ + t) * H_ + n_lane];

        unsigned short* bufp = &lds_h[t & 1][0];

        if (t > 0) {
            const unsigned tu = (unsigned)t;
            unsigned long long* src = exch + (size_t)(group * 2 + (t & 1)) * 2048;
            unsigned long long uv[8];
            unsigned pending = 0xffu;
            while (pending) {
#pragma unroll
                for (int i = 0; i < 8; ++i)
                    if (pending & (1u << i))
                        uv[i] = __hip_atomic_load(src + tid + i * 256,
                                                  __ATOMIC_RELAXED, __HIP_MEMORY_SCOPE_AGENT);
#pragma unroll
                for (int i = 0; i < 8; ++i)
                    if ((pending & (1u << i)) && (unsigned)(uv[i] >> 32) == tu)
                        pending &= ~(1u << i);
            }
            // stage fresh h_t into LDS (already bf16 hi/lo packed by producer)
#pragma unroll
            for (int i = 0; i < 8; ++i) {
                const int idx = tid + i * 256;
                const int r = idx >> 9, c = idx & 511;
                const unsigned pv = (unsigned)(uv[i] & 0xffffffffu);
                bufp[r * 520 + c]       = (unsigned short)(pv >> 16);
                bufp[(r + 4) * 520 + c] = (unsigned short)(pv & 0xffffu);
            }
        }
        __syncthreads();   // staging of buf[t&1] visible to all waves

        // ---- prefetch all A-fragments, then MFMA (2 interleaved chains) ----
        bf16x8 fr[16];
#pragma unroll
        for (int kk = 0; kk < 16; ++kk)
            fr[kk] = *(const bf16x8*)(&bufp[rr * 520 + kk * 32 + quad * 8]);

        floatx4 ae = (floatx4){0.f, 0.f, 0.f, 0.f};
        floatx4 ao = (floatx4){0.f, 0.f, 0.f, 0.f};
#pragma unroll
        for (int kk = 0; kk < 16; kk += 2) {
            ae = __builtin_amdgcn_mfma_f32_16x16x32_bf16(fr[kk],     wf[kk],     ae, 0, 0, 0);
            ao = __builtin_amdgcn_mfma_f32_16x16x32_bf16(fr[kk + 1], wf[kk + 1], ao, 0, 0, 0);
        }
        // no second barrier: next-step staging targets the other LDS buffer

        // ---- epilogue ----
        // D rows: quad*4+i.  hi contribution rows 0-3 (quad 0), lo rows 4-7
        // (quad 1).  Sum hi+lo across the quad0<->quad1 split, then spread
        // batch i's value to quad i lanes.
        float c0 = ae[0] + ao[0], c1 = ae[1] + ao[1];
        float c2 = ae[2] + ao[2], c3 = ae[3] + ao[3];
        c0 += __shfl_xor(c0, 16);
        c1 += __shfl_xor(c1, 16);
        c2 += __shfl_xor(c2, 16);
        c3 += __shfl_xor(c3, 16);
        const int srcl = lane & 15;
        const float s0 = __shfl(c0, srcl);
        const float s1 = __shfl(c1, srcl);
        const float s2 = __shfl(c2, srcl);
        const float s3 = __shfl(c3, srcl);
        float pre = (quad == 0) ? s0 : ((quad == 1) ? s1 : ((quad == 2) ? s2 : s3));
        pre += xpv + bias_v;
        const float e2 = __expf(pre + pre);
        const float hval = 1.0f - 2.0f / (e2 + 1.0f);   // tanh(pre)

        // producer-side bf16 hi/lo split, packed with the tag
        const unsigned short hv = f2bf(hval);
        const unsigned short lv = f2bf(hval - bf2f(hv));

        // publish slice of h_{t+1}: single atomic u64 = (tag<<32)|hi16|lo16.
        {
            unsigned long long* dst = exch + (size_t)(group * 2 + ((t + 1) & 1)) * 2048
                                    + (size_t)quad * 512 + n_lane;
            const unsigned long long pk =
                ((unsigned long long)(unsigned)(t + 1) << 32) |
                ((unsigned long long)hv << 16) |
                (unsigned long long)lv;
            __hip_atomic_store(dst, pk, __ATOMIC_RELAXED, __HIP_MEMORY_SCOPE_AGENT);
        }

        // h_n output store (fire-and-forget, off critical path)
        hn[((long)b_lane * L_ + t) * H_ + n_lane] = hval;
    }
}

// ---------------------------------------------------------------------------
extern "C" void kernel_launch(void* const* d_in, const int* in_sizes, int n_in,
                              void* d_out, int out_size, void* d_ws, size_t ws_size,
                              hipStream_t stream)
{
    const float* inputs = (const float*)d_in[0];
    const float* hidden = (const float*)d_in[1];
    const float* Wi     = (const float*)d_in[2];
    const float* bi     = (const float*)d_in[3];
    const float* Wh     = (const float*)d_in[4];
    const float* bh     = (const float*)d_in[5];
    const float* Wo     = (const float*)d_in[6];
    const float* bo     = (const float*)d_in[7];

    float* out = (float*)d_out;
    float* xp  = out;                                   // scratch: overwritten by phase 3
    float* hn  = out + (long)B_ * L_ * C_;              // h_n output region

    // clear exchange tags (stale-tag poison from prior replay never matches t>=1)
    hipMemsetAsync(d_ws, 0, (size_t)8 * 2 * 2048 * 8, stream);

    // Phase 1: x_proj = inputs * Wi^T + bi   -> xp [65536 x 512]
    gemm_bias<<<dim3(4, 512), 256, 0, stream>>>(inputs, Wi, bi, xp, 512, 512);

    // Phase 2: sequential recurrence -> hn [32 x 2048 x 512]
    rnn_scan<<<dim3(64), 256, 0, stream>>>(Wh, bh, hidden, xp, hn,
                                           (unsigned long long*)d_ws);

    // Phase 3: output = h_n * Wo^T + bo -> out [65536 x 1000] (overwrites xp)
    gemm_bias<<<dim3(8, 512), 256, 0, stream>>>(hn, Wo, bo, out, 1000, 1000);
}